// Round 12
// baseline (244.186 us; speedup 1.0000x reference)
//
#include <hip/hip_runtime.h>
#include <hip/hip_bf16.h>

// N=8192 points, k=8 exact kNN -> mean |plane distance|.
// R12: MFMA-filtered exact kNN + fused last-block finalize.
//   d2(r,c) = sq_r + sq_c - 2 p_r.q_c via 16x16x32 bf16 MFMA, hi/lo split:
//   K slots: hh/hl/lh per dim, laz*hz, 1*(hs_c,ls_c), (hsr,lsr)*1 -> acc = d2
//   estimate (err <~ 0.004 abs). Margin 0.02+2e-3*T keeps filter a guaranteed
//   superset; survivors re-scored exactly in f32 -> selection exact.
#define NPTS 8192
#define KNN 8
#define NBC 8             // col-slices per 64-row group
#define CPB 1024          // cols per mfma block
#define TSEG 8            // threshold sample classes (waves in prep)

typedef __attribute__((ext_vector_type(8))) short bf16x8;
typedef __attribute__((ext_vector_type(4))) float f32x4;

__device__ __forceinline__ unsigned int bf16rne(float x) {
    unsigned int u = __float_as_uint(x);
    return (u + 0x7FFFu + ((u >> 16) & 1u)) >> 16;
}
__device__ __forceinline__ float bf2f(unsigned int h) { return __uint_as_float(h << 16); }

__device__ __forceinline__ void insert8(unsigned int (&best)[KNN], unsigned int key) {
#pragma unroll
    for (int t = 0; t < KNN; ++t) {
        const unsigned int lo = min(best[t], key);
        key = max(best[t], key);
        best[t] = lo;
    }
}

// Pack pts + B-fragments, zero out/cnt, per-point threshold from 512 strided
// samples (8 waves x 64 wave-uniform scalar loads; per-thread top-4 -> merge).
__global__ __launch_bounds__(512) void prep_thresh(const float* __restrict__ means,
                                                   float4* __restrict__ pts,
                                                   uint4* __restrict__ bfragB,
                                                   float* __restrict__ Tm_arr,
                                                   int* __restrict__ cnt,
                                                   float* __restrict__ out) {
    __shared__ unsigned int lds_k[TSEG][64][5];  // 4 keys/thread (+pad)
    const int tid = threadIdx.x;
    const int l = tid & 63;
    const int wv = __builtin_amdgcn_readfirstlane(tid >> 6);
    const int pt = blockIdx.x * 64 + l;
    if (blockIdx.x == 0 && tid == 0) out[0] = 0.0f;
    if (blockIdx.x == 0 && tid < NPTS / 64) cnt[tid] = 0;  // re-zeroed every launch

    const float x = means[3 * pt + 0];
    const float y = means[3 * pt + 1];
    const float z = means[3 * pt + 2];
    const float sq = x * x + y * y + z * z;
    if (wv == 0) {
        pts[pt] = make_float4(x, y, z, sq);
        const unsigned int hx = bf16rne(x), lx = bf16rne(x - bf2f(hx));
        const unsigned int hy = bf16rne(y), ly = bf16rne(y - bf2f(hy));
        const unsigned int hz = bf16rne(z), lz = bf16rne(z - bf2f(hz));
        const unsigned int hs = bf16rne(sq), ls = bf16rne(sq - bf2f(hs));
        // B g0: [hx,lx,hx, hy,ly,hy, hz,lz]   g1: [hz, hs, ls, 1, 1, 0,0,0]
        bfragB[pt * 2 + 0] = make_uint4(hx | (lx << 16), hx | (hy << 16),
                                        ly | (hy << 16), hz | (lz << 16));
        bfragB[pt * 2 + 1] = make_uint4(hz | (hs << 16), ls | (0x3F80u << 16), 0x3F80u, 0u);
    }

    // 64 samples/thread at cols 16*(wv + 8m): wave-uniform -> scalar loads
    const float mx2 = -2.0f * x, my2 = -2.0f * y, mz2 = -2.0f * z;
    unsigned int b4[4] = {0xFFFFFFFFu, 0xFFFFFFFFu, 0xFFFFFFFFu, 0xFFFFFFFFu};
#pragma unroll 4
    for (int m = 0; m < 64; ++m) {
        const int col = 16 * (wv + TSEG * m);
        const float qx = means[3 * col + 0];
        const float qy = means[3 * col + 1];
        const float qz = means[3 * col + 2];
        const float qsq = qx * qx + qy * qy + qz * qz;
        const float d2 = fmaxf(fmaf(mx2, qx, fmaf(my2, qy, fmaf(mz2, qz, sq + qsq))), 0.0f);
        unsigned int key = (__float_as_uint(d2) & 0xFFFFE000u) | (unsigned int)col;
        key = (col == pt) ? 0xFFFFFFFFu : key;
#pragma unroll
        for (int t = 0; t < 4; ++t) {  // per-thread top-4 (union still bounds 8th)
            const unsigned int lo = min(b4[t], key);
            key = max(b4[t], key);
            b4[t] = lo;
        }
    }
#pragma unroll
    for (int s = 0; s < 4; ++s) lds_k[wv][l][s] = b4[s];
    __syncthreads();
    if (wv == 0) {
        unsigned int best[KNN] = {b4[0], b4[1], b4[2], b4[3],
                                  0xFFFFFFFFu, 0xFFFFFFFFu, 0xFFFFFFFFu, 0xFFFFFFFFu};
#pragma unroll
        for (int w = 1; w < TSEG; ++w)
#pragma unroll
            for (int s = 0; s < 4; ++s) insert8(best, lds_k[w][l][s]);
        const float Tf = __uint_as_float(best[7] & 0xFFFFE000u);
        Tm_arr[pt] = Tf + 0.02f + 2e-3f * Tf;  // covers trunc + mfma error
    }
}

// Per block: 64 rows x 1024 cols. MFMA filter -> bitmask -> decode + exact
// re-score -> per-row slice top-8 -> part. Last block of each row-group merges
// the 8 partials, computes plane distances, reduces, atomicAdd.
__global__ __launch_bounds__(256) void mfma_knn(const float4* __restrict__ pts,
                                                const float* __restrict__ normals,
                                                const uint4* __restrict__ bfragB,
                                                const float* __restrict__ Tm_arr,
                                                unsigned int* __restrict__ part,
                                                int* __restrict__ cnt,
                                                float* __restrict__ out) {
    __shared__ uint4 lds_b[CPB * 2];              // 32 KB, flat [col*2 + kgrp]
    __shared__ unsigned int lds_bits[4][64][8];   // 8 KB; reused by finalize
    __shared__ int lastFlag;
    const int tid = threadIdx.x;
    const int l = tid & 63;
    const int wv = __builtin_amdgcn_readfirstlane(tid >> 6);
    const int rp = blockIdx.x >> 3;
    const int cbi = blockIdx.x & 7;
    const int cb = cbi * CPB;
    {   // stage B frags: 2048 uint4, coalesced
        const uint4* __restrict__ src = bfragB + cb * 2;
#pragma unroll
        for (int k = 0; k < 8; ++k) lds_b[tid + 256 * k] = src[tid + 256 * k];
    }
    const int rbase = rp * 64 + wv * 16;
    const int arow = rbase + (l & 15);
    const int g = l >> 4;
    const float4 mp = pts[arow];
    const float ax = -2.0f * mp.x, ay = -2.0f * mp.y, az = -2.0f * mp.z;
    const unsigned int hax = bf16rne(ax), lax = bf16rne(ax - bf2f(hax));
    const unsigned int hay = bf16rne(ay), lay = bf16rne(ay - bf2f(hay));
    const unsigned int haz = bf16rne(az), laz = bf16rne(az - bf2f(haz));
    const unsigned int hsr = bf16rne(mp.w), lsr = bf16rne(mp.w - bf2f(hsr));
    // A g0: [hax,hax,lax, hay,hay,lay, haz,haz]  g1: [laz, 1, 1, hsr, lsr, 0,0,0]
    uint4 au = make_uint4(0u, 0u, 0u, 0u);
    if (g == 0) au = make_uint4(hax | (hax << 16), lax | (hay << 16),
                                hay | (lay << 16), haz | (haz << 16));
    if (g == 1) au = make_uint4(laz | (0x3F80u << 16), 0x3F80u | (hsr << 16), lsr, 0u);
    union { uint4 u; bf16x8 v; } A; A.u = au;
    float Tm[4];
#pragma unroll
    for (int r = 0; r < 4; ++r) Tm[r] = Tm_arr[rbase + g * 4 + r];  // C row = g*4+r
    __syncthreads();

    // lanes 32-63 broadcast-read the same B as 0-31 (A zero in k16-31).
    const int bidx = (l & 15) * 2 + (g & 1);
    const f32x4 zero = {0.0f, 0.0f, 0.0f, 0.0f};
    unsigned int m0[4], m1[4];
#pragma unroll
    for (int r = 0; r < 4; ++r) { m0[r] = 0u; m1[r] = 0u; }
#pragma unroll 4
    for (int t2 = 0; t2 < 32; ++t2) {
        union { uint4 u; bf16x8 v; } B; B.u = lds_b[t2 * 32 + bidx];
        const f32x4 acc = __builtin_amdgcn_mfma_f32_16x16x32_bf16(A.v, B.v, zero, 0, 0, 0);
#pragma unroll
        for (int r = 0; r < 4; ++r) m0[r] = m0[r] * 2u + ((acc[r] <= Tm[r]) ? 1u : 0u);
    }
#pragma unroll 4
    for (int t2 = 0; t2 < 32; ++t2) {
        union { uint4 u; bf16x8 v; } B; B.u = lds_b[(32 + t2) * 32 + bidx];
        const f32x4 acc = __builtin_amdgcn_mfma_f32_16x16x32_bf16(A.v, B.v, zero, 0, 0, 0);
#pragma unroll
        for (int r = 0; r < 4; ++r) m1[r] = m1[r] * 2u + ((acc[r] <= Tm[r]) ? 1u : 0u);
    }
#pragma unroll
    for (int r = 0; r < 4; ++r) {
        lds_bits[wv][l][r * 2 + 0] = m0[r];
        lds_bits[wv][l][r * 2 + 1] = m1[r];
    }
    __syncthreads();

    // decode: lane handles row (l&15), col-classes 4*(l>>4)..+3
    unsigned int best[KNN];
#pragma unroll
    for (int s = 0; s < KNN; ++s) best[s] = 0xFFFFFFFFu;
    const int LR = l & 15;
    const int slb = (LR >> 2) * 16;
    const int wb = (LR & 3) * 2;
#pragma unroll
    for (int cc = 0; cc < 4; ++cc) {
        const int cl = (l >> 4) * 4 + cc;
        const int sl = slb + cl;
#pragma unroll
        for (int ch = 0; ch < 2; ++ch) {
            unsigned int w = lds_bits[wv][sl][wb + ch];
            while (w) {
                const int b = __ffs(w) - 1;
                w &= w - 1;
                const int ct2 = 31 - b;
                const int col = cb + (ch * 32 + ct2) * 16 + cl;
                const float4 q = pts[col];
                const float d2 = fmaxf(fmaf(ax, q.x, fmaf(ay, q.y, fmaf(az, q.z, mp.w + q.w))), 0.0f);
                unsigned int key = (__float_as_uint(d2) & 0xFFFFE000u) | (unsigned int)col;
                key = (col == arow) ? 0xFFFFFFFFu : key;
                insert8(best, key);
            }
        }
    }
    // merge the 4 lanes sharing this row (xor 16, then 32)
#pragma unroll
    for (int st = 16; st <= 32; st <<= 1) {
        unsigned int tk[KNN];
#pragma unroll
        for (int s = 0; s < KNN; ++s) tk[s] = __shfl_xor(best[s], st);
#pragma unroll
        for (int s = 0; s < KNN; ++s) insert8(best, tk[s]);
    }
    if (l < 16) {
        uint4* dst = (uint4*)(part + ((unsigned int)arow * 8u + (unsigned int)cbi) * 8u);
        dst[0] = make_uint4(best[0], best[1], best[2], best[3]);
        dst[1] = make_uint4(best[4], best[5], best[6], best[7]);
    }

    // ---- last-block finalize for this 64-row group ----
    __threadfence();          // publish part writes device-wide
    __syncthreads();          // all threads' stores+fences done
    if (tid == 0) lastFlag = (atomicAdd(&cnt[rp], 1) == NBC - 1) ? 1 : 0;
    __syncthreads();
    if (!lastFlag) return;
    __threadfence();          // acquire: other blocks' part writes

    const int frow = rp * 64 + (tid & 63);
    const int grp = tid >> 6;  // 2 slices each
    unsigned int bb[KNN];
#pragma unroll
    for (int s = 0; s < KNN; ++s) bb[s] = 0xFFFFFFFFu;
    const uint4* __restrict__ P = (const uint4*)(part + (unsigned int)frow * 64u) + grp * 4;
#pragma unroll
    for (int b = 0; b < 4; ++b) {
        const uint4 v = P[b];
        insert8(bb, v.x); insert8(bb, v.y); insert8(bb, v.z); insert8(bb, v.w);
    }
#pragma unroll
    for (int s = 0; s < KNN; ++s) lds_bits[grp][tid & 63][s] = bb[s];
    __syncthreads();
    if (tid < 64) {
#pragma unroll
        for (int g2 = 1; g2 < 4; ++g2)
#pragma unroll
            for (int s = 0; s < KNN; ++s) insert8(bb, lds_bits[g2][tid][s]);
        const float4 mpr = pts[frow];
        const float nx = normals[3 * frow + 0];
        const float ny = normals[3 * frow + 1];
        const float nz = normals[3 * frow + 2];
        float sum = 0.0f;
#pragma unroll
        for (int s = 0; s < KNN; ++s) {
            const int nbr = (int)(bb[s] & 0x1FFFu);
            const float4 q = pts[nbr];
            sum += fabsf((q.x - mpr.x) * nx + (q.y - mpr.y) * ny + (q.z - mpr.z) * nz);
        }
#pragma unroll
        for (int off = 32; off > 0; off >>= 1) sum += __shfl_down(sum, off);
        if (tid == 0) atomicAdd(out, sum * (1.0f / ((float)NPTS * (float)KNN)));
    }
}

extern "C" void kernel_launch(void* const* d_in, const int* in_sizes, int n_in,
                              void* d_out, int out_size, void* d_ws, size_t ws_size,
                              hipStream_t stream) {
    const float* means = (const float*)d_in[0];
    const float* normals = (const float*)d_in[1];
    float* out = (float*)d_out;
    char* ws = (char*)d_ws;
    float4* pts = (float4*)ws;                              // 128 KB
    uint4* bfragB = (uint4*)(ws + 131072);                  // 256 KB
    float* Tm = (float*)(ws + 393216);                      // 32 KB
    unsigned int* part = (unsigned int*)(ws + 425984);      // 2 MB
    int* cnt = (int*)(ws + 2523136);                        // 512 B

    prep_thresh<<<NPTS / 64, 512, 0, stream>>>(means, pts, bfragB, Tm, cnt, out);
    mfma_knn<<<(NPTS / 64) * NBC, 256, 0, stream>>>(pts, normals, bfragB, Tm, part, cnt, out);
}

// Round 13
// 42.511 us; speedup vs baseline: 5.7440x; 5.7440x over previous
//
#include <hip/hip_runtime.h>
#include <hip/hip_bf16.h>

// N=8192 points, k=8 exact kNN -> mean |plane distance|.
// R13: MFMA-filtered exact kNN; 3-kernel pipeline (separate launches are the
// device-wide barrier -- R12's __threadfence last-block fusion flushed L2 on
// every block, 5x regression).
//   d2(r,c) = sq_r + sq_c - 2 p_r.q_c via 16x16x32 bf16 MFMA, hi/lo split:
//   acc = d2 estimate (err <~ 0.004 abs). Margin 0.02+2e-3*T keeps the filter
//   a guaranteed superset; survivors re-scored exactly in f32 -> exact.
#define NPTS 8192
#define KNN 8
#define NBC 16            // col-slices per 64-row group
#define CPB 512           // cols per mfma block (16KB B-tile -> ~7 blocks/CU)
#define TSEG 8            // threshold sample waves

typedef __attribute__((ext_vector_type(8))) short bf16x8;
typedef __attribute__((ext_vector_type(4))) float f32x4;

__device__ __forceinline__ unsigned int bf16rne(float x) {
    unsigned int u = __float_as_uint(x);
    return (u + 0x7FFFu + ((u >> 16) & 1u)) >> 16;
}
__device__ __forceinline__ float bf2f(unsigned int h) { return __uint_as_float(h << 16); }

__device__ __forceinline__ void insert8(unsigned int (&best)[KNN], unsigned int key) {
#pragma unroll
    for (int t = 0; t < KNN; ++t) {
        const unsigned int lo = min(best[t], key);
        key = max(best[t], key);
        best[t] = lo;
    }
}

// Pack pts + B-fragments, zero out, per-point threshold from 512 strided
// samples (8 waves x 64 wave-uniform scalar loads; per-thread top-4 -> merge).
__global__ __launch_bounds__(512) void prep_thresh(const float* __restrict__ means,
                                                   float4* __restrict__ pts,
                                                   uint4* __restrict__ bfragB,
                                                   float* __restrict__ Tm_arr,
                                                   float* __restrict__ out) {
    __shared__ unsigned int lds_k[TSEG][64][5];  // 4 keys/thread (+pad)
    const int tid = threadIdx.x;
    const int l = tid & 63;
    const int wv = __builtin_amdgcn_readfirstlane(tid >> 6);
    const int pt = blockIdx.x * 64 + l;
    if (blockIdx.x == 0 && tid == 0) out[0] = 0.0f;

    const float x = means[3 * pt + 0];
    const float y = means[3 * pt + 1];
    const float z = means[3 * pt + 2];
    const float sq = x * x + y * y + z * z;
    if (wv == 0) {
        pts[pt] = make_float4(x, y, z, sq);
        const unsigned int hx = bf16rne(x), lx = bf16rne(x - bf2f(hx));
        const unsigned int hy = bf16rne(y), ly = bf16rne(y - bf2f(hy));
        const unsigned int hz = bf16rne(z), lz = bf16rne(z - bf2f(hz));
        const unsigned int hs = bf16rne(sq), ls = bf16rne(sq - bf2f(hs));
        // B g0: [hx,lx,hx, hy,ly,hy, hz,lz]   g1: [hz, hs, ls, 1, 1, 0,0,0]
        bfragB[pt * 2 + 0] = make_uint4(hx | (lx << 16), hx | (hy << 16),
                                        ly | (hy << 16), hz | (lz << 16));
        bfragB[pt * 2 + 1] = make_uint4(hz | (hs << 16), ls | (0x3F80u << 16), 0x3F80u, 0u);
    }

    // 64 samples/thread at cols 16*(wv + 8m): wave-uniform -> scalar loads
    const float mx2 = -2.0f * x, my2 = -2.0f * y, mz2 = -2.0f * z;
    unsigned int b4[4] = {0xFFFFFFFFu, 0xFFFFFFFFu, 0xFFFFFFFFu, 0xFFFFFFFFu};
#pragma unroll 4
    for (int m = 0; m < 64; ++m) {
        const int col = 16 * (wv + TSEG * m);
        const float qx = means[3 * col + 0];
        const float qy = means[3 * col + 1];
        const float qz = means[3 * col + 2];
        const float qsq = qx * qx + qy * qy + qz * qz;
        const float d2 = fmaxf(fmaf(mx2, qx, fmaf(my2, qy, fmaf(mz2, qz, sq + qsq))), 0.0f);
        unsigned int key = (__float_as_uint(d2) & 0xFFFFE000u) | (unsigned int)col;
        key = (col == pt) ? 0xFFFFFFFFu : key;
#pragma unroll
        for (int t = 0; t < 4; ++t) {  // per-thread top-4 (union still bounds the 8th)
            const unsigned int lo = min(b4[t], key);
            key = max(b4[t], key);
            b4[t] = lo;
        }
    }
#pragma unroll
    for (int s = 0; s < 4; ++s) lds_k[wv][l][s] = b4[s];
    __syncthreads();
    if (wv == 0) {
        unsigned int best[KNN] = {b4[0], b4[1], b4[2], b4[3],
                                  0xFFFFFFFFu, 0xFFFFFFFFu, 0xFFFFFFFFu, 0xFFFFFFFFu};
#pragma unroll
        for (int w = 1; w < TSEG; ++w)
#pragma unroll
            for (int s = 0; s < 4; ++s) insert8(best, lds_k[w][l][s]);
        const float Tf = __uint_as_float(best[7] & 0xFFFFE000u);
        Tm_arr[pt] = Tf + 0.02f + 2e-3f * Tf;  // covers trunc + mfma error
    }
}

// Per block: 64 rows x 512 cols. MFMA filter -> 1-word bitmask per row-slice
// -> decode + exact re-score -> per-row slice top-8 -> part[row][cbi][8].
__global__ __launch_bounds__(256) void mfma_knn(const float4* __restrict__ pts,
                                                const uint4* __restrict__ bfragB,
                                                const float* __restrict__ Tm_arr,
                                                unsigned int* __restrict__ part) {
    __shared__ uint4 lds_b[CPB * 2];              // 16 KB, flat [col*2 + kgrp]
    __shared__ unsigned int lds_bits[4][64][5];   // 5 KB (+pad: conflict-free)
    const int tid = threadIdx.x;
    const int l = tid & 63;
    const int wv = __builtin_amdgcn_readfirstlane(tid >> 6);
    const int rp = blockIdx.x >> 4;
    const int cbi = blockIdx.x & 15;
    const int cb = cbi * CPB;
    {   // stage B frags: 1024 uint4, coalesced
        const uint4* __restrict__ src = bfragB + cb * 2;
#pragma unroll
        for (int k = 0; k < 4; ++k) lds_b[tid + 256 * k] = src[tid + 256 * k];
    }
    const int rbase = rp * 64 + wv * 16;
    const int arow = rbase + (l & 15);
    const int g = l >> 4;
    const float4 mp = pts[arow];
    const float ax = -2.0f * mp.x, ay = -2.0f * mp.y, az = -2.0f * mp.z;
    const unsigned int hax = bf16rne(ax), lax = bf16rne(ax - bf2f(hax));
    const unsigned int hay = bf16rne(ay), lay = bf16rne(ay - bf2f(hay));
    const unsigned int haz = bf16rne(az), laz = bf16rne(az - bf2f(haz));
    const unsigned int hsr = bf16rne(mp.w), lsr = bf16rne(mp.w - bf2f(hsr));
    // A g0: [hax,hax,lax, hay,hay,lay, haz,haz]  g1: [laz, 1, 1, hsr, lsr, 0,0,0]
    uint4 au = make_uint4(0u, 0u, 0u, 0u);
    if (g == 0) au = make_uint4(hax | (hax << 16), lax | (hay << 16),
                                hay | (lay << 16), haz | (haz << 16));
    if (g == 1) au = make_uint4(laz | (0x3F80u << 16), 0x3F80u | (hsr << 16), lsr, 0u);
    union { uint4 u; bf16x8 v; } A; A.u = au;
    float Tm[4];
#pragma unroll
    for (int r = 0; r < 4; ++r) Tm[r] = Tm_arr[rbase + g * 4 + r];  // C row = g*4+r
    __syncthreads();

    // lanes 32-63 broadcast-read the same B as 0-31 (A zero in k16-31).
    const int bidx = (l & 15) * 2 + (g & 1);
    const f32x4 zero = {0.0f, 0.0f, 0.0f, 0.0f};
    unsigned int m0[4];
#pragma unroll
    for (int r = 0; r < 4; ++r) m0[r] = 0u;
#pragma unroll 4
    for (int t2 = 0; t2 < 32; ++t2) {
        union { uint4 u; bf16x8 v; } B; B.u = lds_b[t2 * 32 + bidx];
        const f32x4 acc = __builtin_amdgcn_mfma_f32_16x16x32_bf16(A.v, B.v, zero, 0, 0, 0);
#pragma unroll
        for (int r = 0; r < 4; ++r) m0[r] = m0[r] * 2u + ((acc[r] <= Tm[r]) ? 1u : 0u);
    }
#pragma unroll
    for (int r = 0; r < 4; ++r) lds_bits[wv][l][r] = m0[r];
    __syncthreads();

    // decode: lane handles row (l&15), col-classes 4*(l>>4)..+3
    unsigned int best[KNN];
#pragma unroll
    for (int s = 0; s < KNN; ++s) best[s] = 0xFFFFFFFFu;
    const int LR = l & 15;
#pragma unroll
    for (int cc = 0; cc < 4; ++cc) {
        const int cl = (l >> 4) * 4 + cc;
        unsigned int w = lds_bits[wv][(LR >> 2) * 16 + cl][LR & 3];
        while (w) {
            const int b = __ffs(w) - 1;
            w &= w - 1;
            const int ct2 = 31 - b;
            const int col = cb + ct2 * 16 + cl;
            const float4 q = pts[col];
            const float d2 = fmaxf(fmaf(ax, q.x, fmaf(ay, q.y, fmaf(az, q.z, mp.w + q.w))), 0.0f);
            unsigned int key = (__float_as_uint(d2) & 0xFFFFE000u) | (unsigned int)col;
            key = (col == arow) ? 0xFFFFFFFFu : key;
            insert8(best, key);
        }
    }
    // merge the 4 lanes sharing this row (xor 16, then 32)
#pragma unroll
    for (int st = 16; st <= 32; st <<= 1) {
        unsigned int tk[KNN];
#pragma unroll
        for (int s = 0; s < KNN; ++s) tk[s] = __shfl_xor(best[s], st);
#pragma unroll
        for (int s = 0; s < KNN; ++s) insert8(best, tk[s]);
    }
    if (l < 16) {
        uint4* dst = (uint4*)(part + ((unsigned int)arow * (unsigned int)NBC + (unsigned int)cbi) * 8u);
        dst[0] = make_uint4(best[0], best[1], best[2], best[3]);
        dst[1] = make_uint4(best[4], best[5], best[6], best[7]);
    }
}

// Merge 16 slice-partials per row, plane distance, reduce.
__global__ __launch_bounds__(256) void final_kernel(const float4* __restrict__ pts,
                                                    const float* __restrict__ normals,
                                                    const unsigned int* __restrict__ part,
                                                    float* __restrict__ out) {
    __shared__ float red[4];
    const int row = blockIdx.x * 256 + threadIdx.x;
    unsigned int best[KNN];
#pragma unroll
    for (int s = 0; s < KNN; ++s) best[s] = 0xFFFFFFFFu;
    const uint4* __restrict__ P = (const uint4*)(part + (unsigned int)row * (unsigned int)(NBC * 8));
#pragma unroll
    for (int b = 0; b < NBC * 2; ++b) {
        const uint4 v = P[b];
        insert8(best, v.x); insert8(best, v.y); insert8(best, v.z); insert8(best, v.w);
    }
    const float4 mp = pts[row];
    const float nx = normals[3 * row + 0], ny = normals[3 * row + 1], nz = normals[3 * row + 2];
    float sum = 0.0f;
#pragma unroll
    for (int s = 0; s < KNN; ++s) {
        const int nbr = (int)(best[s] & 0x1FFFu);
        const float4 q = pts[nbr];
        sum += fabsf((q.x - mp.x) * nx + (q.y - mp.y) * ny + (q.z - mp.z) * nz);
    }
    float v = sum;
#pragma unroll
    for (int off = 32; off > 0; off >>= 1) v += __shfl_down(v, off);
    if ((threadIdx.x & 63) == 0) red[threadIdx.x >> 6] = v;
    __syncthreads();
    if (threadIdx.x == 0)
        atomicAdd(out, (red[0] + red[1] + red[2] + red[3]) * (1.0f / ((float)NPTS * (float)KNN)));
}

extern "C" void kernel_launch(void* const* d_in, const int* in_sizes, int n_in,
                              void* d_out, int out_size, void* d_ws, size_t ws_size,
                              hipStream_t stream) {
    const float* means = (const float*)d_in[0];
    const float* normals = (const float*)d_in[1];
    float* out = (float*)d_out;
    char* ws = (char*)d_ws;
    float4* pts = (float4*)ws;                              // 128 KB
    uint4* bfragB = (uint4*)(ws + 131072);                  // 256 KB
    float* Tm = (float*)(ws + 393216);                      // 32 KB
    unsigned int* part = (unsigned int*)(ws + 425984);      // 4 MB

    prep_thresh<<<NPTS / 64, 512, 0, stream>>>(means, pts, bfragB, Tm, out);
    mfma_knn<<<(NPTS / 64) * NBC, 256, 0, stream>>>(pts, bfragB, Tm, part);
    final_kernel<<<NPTS / 256, 256, 0, stream>>>(pts, normals, part, out);
}